// Round 1
// baseline (6434.745 us; speedup 1.0000x reference)
//
#include <hip/hip_runtime.h>

#define N_NODES 100000
#define N_EDGES 1600000

// ---------------- degree / norm ----------------
__global__ void deg_kernel(const int* __restrict__ dst, int* __restrict__ deg, int E) {
    int i = blockIdx.x * blockDim.x + threadIdx.x;
    if (i < E) atomicAdd(&deg[dst[i]], 1);
}

__global__ void dinv_kernel(const int* __restrict__ deg, float* __restrict__ dinv, int n) {
    int i = blockIdx.x * blockDim.x + threadIdx.x;
    if (i < n) dinv[i] = rsqrtf((float)(deg[i] + 1));   // +1 = self-loop
}

__global__ void norm_kernel(const int* __restrict__ src, const int* __restrict__ dst,
                            const float* __restrict__ dinv, float* __restrict__ nrm, int E) {
    int i = blockIdx.x * blockDim.x + threadIdx.x;
    if (i < E) nrm[i] = dinv[src[i]] * dinv[dst[i]];
}

// ---------------- generic fp32 tiled GEMM ----------------
// C[M,N] = A[M,K] @ B[K,N] (+bias, +relu). 64x64 tile, 256 thr, 4x4 microtile.
// Requires K % 16 == 0, N % 4 == 0.
template<bool ADD_BIAS, bool RELU>
__global__ __launch_bounds__(256) void gemm_kernel(
        const float* __restrict__ A, const float* __restrict__ B,
        const float* __restrict__ bias, float* __restrict__ Cmat,
        int M, int N, int K) {
    __shared__ float As[16][64];   // [k][m]
    __shared__ float Bs[16][64];   // [k][n]
    const int t  = threadIdx.x;
    const int tm = t >> 4, tn = t & 15;
    const int m0 = blockIdx.x * 64;
    const int n0 = blockIdx.y * 64;

    const int arow = t >> 2;          // 0..63
    const int acol = (t & 3) * 4;     // 0,4,8,12
    const int brow = t >> 4;          // 0..15
    const int bcol = (t & 15) * 4;    // 0..60

    float acc[4][4] = {};

    for (int k0 = 0; k0 < K; k0 += 16) {
        float4 a4 = make_float4(0.f, 0.f, 0.f, 0.f);
        if (m0 + arow < M)
            a4 = *(const float4*)&A[(size_t)(m0 + arow) * K + k0 + acol];
        As[acol + 0][arow] = a4.x;
        As[acol + 1][arow] = a4.y;
        As[acol + 2][arow] = a4.z;
        As[acol + 3][arow] = a4.w;

        float4 b4 = make_float4(0.f, 0.f, 0.f, 0.f);
        if (n0 + bcol < N)
            b4 = *(const float4*)&B[(size_t)(k0 + brow) * N + n0 + bcol];
        *(float4*)&Bs[brow][bcol] = b4;

        __syncthreads();
        #pragma unroll
        for (int k = 0; k < 16; ++k) {
            float4 av = *(float4*)&As[k][tm * 4];
            float4 bv = *(float4*)&Bs[k][tn * 4];
            float a[4] = {av.x, av.y, av.z, av.w};
            float b[4] = {bv.x, bv.y, bv.z, bv.w};
            #pragma unroll
            for (int i = 0; i < 4; ++i)
                #pragma unroll
                for (int j = 0; j < 4; ++j)
                    acc[i][j] += a[i] * b[j];
        }
        __syncthreads();
    }

    #pragma unroll
    for (int i = 0; i < 4; ++i) {
        int row = m0 + tm * 4 + i;
        if (row >= M) continue;
        #pragma unroll
        for (int j = 0; j < 4; ++j) {
            int col = n0 + tn * 4 + j;
            if (col >= N) continue;
            float v = acc[i][j];
            if (ADD_BIAS) v += bias[col];
            if (RELU) v = fmaxf(v, 0.f);
            Cmat[(size_t)row * N + col] = v;
        }
    }
}

// ---------------- edge scatter (wave per item, grid-stride) ----------------
// items 0..E-1: real edges; items E..E+n-1: self-loops.
template<int F>
__global__ void scatter_kernel(const int* __restrict__ src, const int* __restrict__ dst,
                               const float* __restrict__ nrm, const float* __restrict__ dinv,
                               const float* __restrict__ xw, float* __restrict__ out,
                               int E, int n) {
    const int lane  = threadIdx.x & 63;
    const int wid0  = (blockIdx.x * blockDim.x + threadIdx.x) >> 6;
    const int nwav  = (gridDim.x * blockDim.x) >> 6;
    const int total = E + n;
    for (int i = wid0; i < total; i += nwav) {
        int s, d; float w;
        if (i < E) { s = src[i]; d = dst[i]; w = nrm[i]; }
        else       { s = d = i - E; float di = dinv[s]; w = di * di; }
        if (F == 256) {
            const float4 v = *(const float4*)&xw[(size_t)s * F + lane * 4];
            float* o = &out[(size_t)d * F + lane * 4];
            atomicAdd(o + 0, v.x * w);
            atomicAdd(o + 1, v.y * w);
            atomicAdd(o + 2, v.z * w);
            atomicAdd(o + 3, v.w * w);
        } else {  // F == 64
            float v = xw[(size_t)s * F + lane];
            atomicAdd(&out[(size_t)d * F + lane], v * w);
        }
    }
}

// ---------------- bias (+relu) finalize ----------------
template<int F, bool RELU>
__global__ void finalize_kernel(float* __restrict__ h, const float* __restrict__ bias, int n) {
    size_t i = (size_t)blockIdx.x * blockDim.x + threadIdx.x;
    size_t tot4 = (size_t)n * F / 4;
    if (i >= tot4) return;
    size_t i4 = i * 4;
    int c = (int)(i4 % F);
    float4 v = *(float4*)&h[i4];
    v.x += bias[c + 0]; v.y += bias[c + 1]; v.z += bias[c + 2]; v.w += bias[c + 3];
    if (RELU) {
        v.x = fmaxf(v.x, 0.f); v.y = fmaxf(v.y, 0.f);
        v.z = fmaxf(v.z, 0.f); v.w = fmaxf(v.w, 0.f);
    }
    *(float4*)&h[i4] = v;
}

extern "C" void kernel_launch(void* const* d_in, const int* in_sizes, int n_in,
                              void* d_out, int out_size, void* d_ws, size_t ws_size,
                              hipStream_t stream) {
    const float* x   = (const float*)d_in[0];
    const int*   ei  = (const int*)d_in[1];
    const float* W1  = (const float*)d_in[2];
    const float* b1  = (const float*)d_in[3];
    const float* W2  = (const float*)d_in[4];
    const float* b2  = (const float*)d_in[5];
    const float* Wfc = (const float*)d_in[6];
    const float* bfc = (const float*)d_in[7];
    float* out = (float*)d_out;

    const int n = N_NODES, E = N_EDGES;
    const int* src = ei;
    const int* dst = ei + E;

    char* ws = (char*)d_ws;
    int*   deg  = (int*)(ws + 0);            // 400 KB
    float* dinv = (float*)(ws + 400000);     // 400 KB
    float* nrm  = (float*)(ws + 800000);     // 6.4 MB
    float* bufA = (float*)(ws + 7200000);    // 102.4 MB  (xw1, then h1w2)
    float* bufB = (float*)(ws + 109600000);  // 102.4 MB  (h1acc/h1, then h2acc/h2)

    // degree + norm (reused by both conv layers)
    hipMemsetAsync(deg, 0, (size_t)n * sizeof(int), stream);
    deg_kernel<<<(E + 255) / 256, 256, 0, stream>>>(dst, deg, E);
    dinv_kernel<<<(n + 255) / 256, 256, 0, stream>>>(deg, dinv, n);
    norm_kernel<<<(E + 255) / 256, 256, 0, stream>>>(src, dst, dinv, nrm, E);

    // layer 1: xw1 = x @ W1  [100k,256]
    gemm_kernel<false, false><<<dim3((n + 63) / 64, 256 / 64), 256, 0, stream>>>(
        x, W1, nullptr, bufA, n, 256, 128);
    hipMemsetAsync(bufB, 0, (size_t)n * 256 * sizeof(float), stream);
    scatter_kernel<256><<<2048, 256, 0, stream>>>(src, dst, nrm, dinv, bufA, bufB, E, n);
    finalize_kernel<256, true><<<((size_t)n * 256 / 4 + 255) / 256, 256, 0, stream>>>(bufB, b1, n);

    // layer 2: h1w2 = h1 @ W2  [100k,64]
    gemm_kernel<false, false><<<dim3((n + 63) / 64, 1), 256, 0, stream>>>(
        bufB, W2, nullptr, bufA, n, 64, 256);
    hipMemsetAsync(bufB, 0, (size_t)n * 64 * sizeof(float), stream);
    scatter_kernel<64><<<2048, 256, 0, stream>>>(src, dst, nrm, dinv, bufA, bufB, E, n);
    finalize_kernel<64, false><<<((size_t)n * 64 / 4 + 255) / 256, 256, 0, stream>>>(bufB, b2, n);

    // FC: out = h2 @ Wfc + bfc  [100k,40]
    gemm_kernel<true, false><<<dim3((n + 63) / 64, 1), 256, 0, stream>>>(
        bufB, Wfc, bfc, out, n, 40, 64);
}

// Round 2
// 757.238 us; speedup vs baseline: 8.4977x; 8.4977x over previous
//
#include <hip/hip_runtime.h>

#define N_NODES 100000
#define N_EDGES 1600000

// ---------------- degree ----------------
__global__ void deg_kernel(const int* __restrict__ dst, int* __restrict__ deg, int E) {
    int i = blockIdx.x * blockDim.x + threadIdx.x;
    if (i < E) atomicAdd(&deg[dst[i]], 1);
}

__global__ void dinv_kernel(const int* __restrict__ deg, float* __restrict__ dinv, int n) {
    int i = blockIdx.x * blockDim.x + threadIdx.x;
    if (i < n) dinv[i] = rsqrtf((float)(deg[i] + 1));   // +1 = self-loop
}

// ---------------- exclusive scan of deg -> rowptr (3 passes) ----------------
// pass 1: per-block (1024 elems) sums
__global__ void scan_sums_kernel(const int* __restrict__ deg, int* __restrict__ bsums, int n) {
    __shared__ int sd[256];
    int t = threadIdx.x;
    int base = blockIdx.x * 1024 + t * 4;
    int s = 0;
    #pragma unroll
    for (int j = 0; j < 4; ++j) { int i = base + j; if (i < n) s += deg[i]; }
    sd[t] = s; __syncthreads();
    for (int off = 128; off > 0; off >>= 1) {
        if (t < off) sd[t] += sd[t + off];
        __syncthreads();
    }
    if (t == 0) bsums[blockIdx.x] = sd[0];
}

// pass 2: exclusive scan of block sums (nb <= 128), single block of 128
__global__ void scan_offsets_kernel(int* __restrict__ bsums, int nb, int* __restrict__ rowptr_tail) {
    __shared__ int sd[128];
    int t = threadIdx.x;
    int v = (t < nb) ? bsums[t] : 0;
    sd[t] = v; __syncthreads();
    for (int off = 1; off < 128; off <<= 1) {
        int x = (t >= off) ? sd[t - off] : 0;
        __syncthreads();
        sd[t] += x;
        __syncthreads();
    }
    if (t < nb) bsums[t] = sd[t] - v;      // exclusive
    if (t == 0) *rowptr_tail = N_EDGES;    // rowptr[n]
}

// pass 3: per-block exclusive scan + block offset
__global__ void scan_final_kernel(const int* __restrict__ deg, const int* __restrict__ bsums,
                                  int* __restrict__ rowptr, int n) {
    __shared__ int sd[256];
    int t = threadIdx.x;
    int base = blockIdx.x * 1024 + t * 4;
    int v[4], pre[4], s = 0;
    #pragma unroll
    for (int j = 0; j < 4; ++j) {
        int i = base + j;
        v[j] = (i < n) ? deg[i] : 0;
        pre[j] = s; s += v[j];
    }
    sd[t] = s;
    int mine = s;
    __syncthreads();
    for (int off = 1; off < 256; off <<= 1) {
        int x = (t >= off) ? sd[t - off] : 0;
        __syncthreads();
        sd[t] += x;
        __syncthreads();
    }
    int excl = sd[t] - mine + bsums[blockIdx.x];
    #pragma unroll
    for (int j = 0; j < 4; ++j) {
        int i = base + j;
        if (i < n) rowptr[i] = excl + pre[j];
    }
}

// ---------------- counting-sort fill ----------------
__global__ void fill_kernel(const int* __restrict__ src, const int* __restrict__ dst,
                            const float* __restrict__ dinv, const int* __restrict__ rowptr,
                            int* __restrict__ cursor, int* __restrict__ csr_src,
                            float* __restrict__ csr_w, int E) {
    int i = blockIdx.x * blockDim.x + threadIdx.x;
    if (i >= E) return;
    int s = src[i], d = dst[i];
    int pos = atomicAdd(&cursor[d], 1);
    int idx = rowptr[d] + pos;
    csr_src[idx] = s;
    csr_w[idx] = dinv[s] * dinv[d];
}

// ---------------- gather (one wave per dst node) ----------------
// acc init = self-loop contribution; bias (+relu) fused.
template<int F, bool RELU>
__global__ void gather_kernel(const int* __restrict__ rowptr, const int* __restrict__ csr_src,
                              const float* __restrict__ csr_w, const float* __restrict__ dinv,
                              const float* __restrict__ xw, const float* __restrict__ bias,
                              float* __restrict__ out, int n) {
    const int lane = threadIdx.x & 63;
    const int wid0 = (blockIdx.x * blockDim.x + threadIdx.x) >> 6;
    const int nwav = (gridDim.x * blockDim.x) >> 6;
    for (int node = wid0; node < n; node += nwav) {
        float di = dinv[node];
        float selfw = di * di;
        int e0 = rowptr[node], e1 = rowptr[node + 1];
        if (F == 256) {
            const float4 sv = *(const float4*)&xw[(size_t)node * F + lane * 4];
            float ax = sv.x * selfw, ay = sv.y * selfw, az = sv.z * selfw, aw = sv.w * selfw;
            for (int e = e0; e < e1; ++e) {
                int s = csr_src[e]; float w = csr_w[e];
                const float4 v = *(const float4*)&xw[(size_t)s * F + lane * 4];
                ax += v.x * w; ay += v.y * w; az += v.z * w; aw += v.w * w;
            }
            const float4 bb = *(const float4*)&bias[lane * 4];
            ax += bb.x; ay += bb.y; az += bb.z; aw += bb.w;
            if (RELU) {
                ax = fmaxf(ax, 0.f); ay = fmaxf(ay, 0.f);
                az = fmaxf(az, 0.f); aw = fmaxf(aw, 0.f);
            }
            *(float4*)&out[(size_t)node * F + lane * 4] = make_float4(ax, ay, az, aw);
        } else {  // F == 64
            float acc = xw[(size_t)node * F + lane] * selfw;
            for (int e = e0; e < e1; ++e) {
                int s = csr_src[e]; float w = csr_w[e];
                acc += xw[(size_t)s * F + lane] * w;
            }
            acc += bias[lane];
            if (RELU) acc = fmaxf(acc, 0.f);
            out[(size_t)node * F + lane] = acc;
        }
    }
}

// ---------------- generic fp32 tiled GEMM ----------------
// C[M,N] = A[M,K] @ B[K,N] (+bias). 64x64 tile, 256 thr, 4x4 microtile. K%16==0.
template<bool ADD_BIAS>
__global__ __launch_bounds__(256) void gemm_kernel(
        const float* __restrict__ A, const float* __restrict__ B,
        const float* __restrict__ bias, float* __restrict__ Cmat,
        int M, int N, int K) {
    __shared__ float As[16][64];   // [k][m]
    __shared__ float Bs[16][64];   // [k][n]
    const int t  = threadIdx.x;
    const int tm = t >> 4, tn = t & 15;
    const int m0 = blockIdx.x * 64;
    const int n0 = blockIdx.y * 64;

    const int arow = t >> 2;
    const int acol = (t & 3) * 4;
    const int brow = t >> 4;
    const int bcol = (t & 15) * 4;

    float acc[4][4] = {};

    for (int k0 = 0; k0 < K; k0 += 16) {
        float4 a4 = make_float4(0.f, 0.f, 0.f, 0.f);
        if (m0 + arow < M)
            a4 = *(const float4*)&A[(size_t)(m0 + arow) * K + k0 + acol];
        As[acol + 0][arow] = a4.x;
        As[acol + 1][arow] = a4.y;
        As[acol + 2][arow] = a4.z;
        As[acol + 3][arow] = a4.w;

        float4 b4 = make_float4(0.f, 0.f, 0.f, 0.f);
        if (n0 + bcol < N)
            b4 = *(const float4*)&B[(size_t)(k0 + brow) * N + n0 + bcol];
        *(float4*)&Bs[brow][bcol] = b4;

        __syncthreads();
        #pragma unroll
        for (int k = 0; k < 16; ++k) {
            float4 av = *(float4*)&As[k][tm * 4];
            float4 bv = *(float4*)&Bs[k][tn * 4];
            float a[4] = {av.x, av.y, av.z, av.w};
            float b[4] = {bv.x, bv.y, bv.z, bv.w};
            #pragma unroll
            for (int i = 0; i < 4; ++i)
                #pragma unroll
                for (int j = 0; j < 4; ++j)
                    acc[i][j] += a[i] * b[j];
        }
        __syncthreads();
    }

    #pragma unroll
    for (int i = 0; i < 4; ++i) {
        int row = m0 + tm * 4 + i;
        if (row >= M) continue;
        #pragma unroll
        for (int j = 0; j < 4; ++j) {
            int col = n0 + tn * 4 + j;
            if (col >= N) continue;
            float v = acc[i][j];
            if (ADD_BIAS) v += bias[col];
            Cmat[(size_t)row * N + col] = v;
        }
    }
}

extern "C" void kernel_launch(void* const* d_in, const int* in_sizes, int n_in,
                              void* d_out, int out_size, void* d_ws, size_t ws_size,
                              hipStream_t stream) {
    const float* x   = (const float*)d_in[0];
    const int*   ei  = (const int*)d_in[1];
    const float* W1  = (const float*)d_in[2];
    const float* b1  = (const float*)d_in[3];
    const float* W2  = (const float*)d_in[4];
    const float* b2  = (const float*)d_in[5];
    const float* Wfc = (const float*)d_in[6];
    const float* bfc = (const float*)d_in[7];
    float* out = (float*)d_out;

    const int n = N_NODES, E = N_EDGES;
    const int* src = ei;
    const int* dst = ei + E;

    char* ws = (char*)d_ws;
    int*   deg     = (int*)(ws + 0);             // 400 KB (later reused as cursor)
    float* dinv    = (float*)(ws + 409600);      // 400 KB
    int*   rowptr  = (int*)(ws + 819200);        // 400,004 B
    int*   bsums   = (int*)(ws + 1228800);       // 512 B
    int*   csr_src = (int*)(ws + 1229312);       // 6.4 MB
    float* csr_w   = (float*)(ws + 7629312);     // 6.4 MB
    float* bufA    = (float*)(ws + 14029312);    // 102.4 MB
    float* bufB    = (float*)(ws + 116429312);   // 102.4 MB  (end ~218.8 MB)

    const int nb = (n + 1023) / 1024;  // 98 scan blocks

    // ---- CSR build (by dst) ----
    hipMemsetAsync(deg, 0, (size_t)n * sizeof(int), stream);
    deg_kernel<<<(E + 255) / 256, 256, 0, stream>>>(dst, deg, E);
    dinv_kernel<<<(n + 255) / 256, 256, 0, stream>>>(deg, dinv, n);
    scan_sums_kernel<<<nb, 256, 0, stream>>>(deg, bsums, n);
    scan_offsets_kernel<<<1, 128, 0, stream>>>(bsums, nb, rowptr + n);
    scan_final_kernel<<<nb, 256, 0, stream>>>(deg, bsums, rowptr, n);
    hipMemsetAsync(deg, 0, (size_t)n * sizeof(int), stream);  // deg -> cursor
    fill_kernel<<<(E + 255) / 256, 256, 0, stream>>>(src, dst, dinv, rowptr, deg, csr_src, csr_w, E);

    // ---- layer 1: xw1 = x @ W1  [100k,256]; gather + bias + relu ----
    gemm_kernel<false><<<dim3((n + 63) / 64, 4), 256, 0, stream>>>(x, W1, nullptr, bufA, n, 256, 128);
    gather_kernel<256, true><<<(n * 64 + 255) / 256, 256, 0, stream>>>(
        rowptr, csr_src, csr_w, dinv, bufA, b1, bufB, n);

    // ---- layer 2: h1w2 = h1 @ W2  [100k,64]; gather + bias ----
    gemm_kernel<false><<<dim3((n + 63) / 64, 1), 256, 0, stream>>>(bufB, W2, nullptr, bufA, n, 64, 256);
    gather_kernel<64, false><<<(n * 64 + 255) / 256, 256, 0, stream>>>(
        rowptr, csr_src, csr_w, dinv, bufA, b2, bufB, n);

    // ---- FC: out = h2 @ Wfc + bfc  [100k,40] ----
    gemm_kernel<true><<<dim3((n + 63) / 64, 1), 256, 0, stream>>>(bufB, Wfc, bfc, out, n, 40, 64);
}

// Round 4
// 648.070 us; speedup vs baseline: 9.9291x; 1.1685x over previous
//
#include <hip/hip_runtime.h>

#define N_NODES 100000
#define N_EDGES 1600000

// ---------------- degree ----------------
__global__ void deg_kernel(const int* __restrict__ dst, int* __restrict__ deg, int E) {
    int i = blockIdx.x * blockDim.x + threadIdx.x;
    if (i < E) atomicAdd(&deg[dst[i]], 1);
}

__global__ void dinv_kernel(const int* __restrict__ deg, float* __restrict__ dinv, int n) {
    int i = blockIdx.x * blockDim.x + threadIdx.x;
    if (i < n) dinv[i] = rsqrtf((float)(deg[i] + 1));   // +1 = self-loop
}

// ---------------- exclusive scan of deg -> rowptr (3 passes) ----------------
__global__ void scan_sums_kernel(const int* __restrict__ deg, int* __restrict__ bsums, int n) {
    __shared__ int sd[256];
    int t = threadIdx.x;
    int base = blockIdx.x * 1024 + t * 4;
    int s = 0;
    #pragma unroll
    for (int j = 0; j < 4; ++j) { int i = base + j; if (i < n) s += deg[i]; }
    sd[t] = s; __syncthreads();
    for (int off = 128; off > 0; off >>= 1) {
        if (t < off) sd[t] += sd[t + off];
        __syncthreads();
    }
    if (t == 0) bsums[blockIdx.x] = sd[0];
}

__global__ void scan_offsets_kernel(int* __restrict__ bsums, int nb, int* __restrict__ rowptr_tail) {
    __shared__ int sd[128];
    int t = threadIdx.x;
    int v = (t < nb) ? bsums[t] : 0;
    sd[t] = v; __syncthreads();
    for (int off = 1; off < 128; off <<= 1) {
        int x = (t >= off) ? sd[t - off] : 0;
        __syncthreads();
        sd[t] += x;
        __syncthreads();
    }
    if (t < nb) bsums[t] = sd[t] - v;      // exclusive
    if (t == 0) *rowptr_tail = N_EDGES;    // rowptr[n]
}

__global__ void scan_final_kernel(const int* __restrict__ deg, const int* __restrict__ bsums,
                                  int* __restrict__ rowptr, int n) {
    __shared__ int sd[256];
    int t = threadIdx.x;
    int base = blockIdx.x * 1024 + t * 4;
    int v[4], pre[4], s = 0;
    #pragma unroll
    for (int j = 0; j < 4; ++j) {
        int i = base + j;
        v[j] = (i < n) ? deg[i] : 0;
        pre[j] = s; s += v[j];
    }
    sd[t] = s;
    int mine = s;
    __syncthreads();
    for (int off = 1; off < 256; off <<= 1) {
        int x = (t >= off) ? sd[t - off] : 0;
        __syncthreads();
        sd[t] += x;
        __syncthreads();
    }
    int excl = sd[t] - mine + bsums[blockIdx.x];
    #pragma unroll
    for (int j = 0; j < 4; ++j) {
        int i = base + j;
        if (i < n) rowptr[i] = excl + pre[j];
    }
}

// ---------------- counting-sort fill ----------------
__global__ void fill_kernel(const int* __restrict__ src, const int* __restrict__ dst,
                            const float* __restrict__ dinv, const int* __restrict__ rowptr,
                            int* __restrict__ cursor, int* __restrict__ csr_src,
                            float* __restrict__ csr_w, int E) {
    int i = blockIdx.x * blockDim.x + threadIdx.x;
    if (i >= E) return;
    int s = src[i], d = dst[i];
    int pos = atomicAdd(&cursor[d], 1);
    int idx = rowptr[d] + pos;
    csr_src[idx] = s;
    csr_w[idx] = dinv[s] * dinv[d];
}

// ---------------- gather (one wave per dst node) ----------------
// F=128: lane owns float2. F=64: lane owns 1 float. Self-loop folded into init.
template<int F, bool BIAS, bool RELU>
__global__ void gather_kernel(const int* __restrict__ rowptr, const int* __restrict__ csr_src,
                              const float* __restrict__ csr_w, const float* __restrict__ dinv,
                              const float* __restrict__ xw, const float* __restrict__ bias,
                              float* __restrict__ out, int n) {
    const int lane = threadIdx.x & 63;
    const int wid0 = (blockIdx.x * blockDim.x + threadIdx.x) >> 6;
    const int nwav = (gridDim.x * blockDim.x) >> 6;
    for (int node = wid0; node < n; node += nwav) {
        float di = dinv[node];
        float selfw = di * di;
        int e0 = rowptr[node], e1 = rowptr[node + 1];
        if (F == 128) {
            const float2 sv = *(const float2*)&xw[(size_t)node * F + lane * 2];
            float ax = sv.x * selfw, ay = sv.y * selfw;
            for (int e = e0; e < e1; ++e) {
                int s = csr_src[e]; float w = csr_w[e];
                const float2 v = *(const float2*)&xw[(size_t)s * F + lane * 2];
                ax += v.x * w; ay += v.y * w;
            }
            if (BIAS) { const float2 bb = *(const float2*)&bias[lane * 2]; ax += bb.x; ay += bb.y; }
            if (RELU) { ax = fmaxf(ax, 0.f); ay = fmaxf(ay, 0.f); }
            *(float2*)&out[(size_t)node * F + lane * 2] = make_float2(ax, ay);
        } else {  // F == 64
            float acc = xw[(size_t)node * F + lane] * selfw;
            for (int e = e0; e < e1; ++e) {
                int s = csr_src[e]; float w = csr_w[e];
                acc += xw[(size_t)s * F + lane] * w;
            }
            if (BIAS) acc += bias[lane];
            if (RELU) acc = fmaxf(acc, 0.f);
            out[(size_t)node * F + lane] = acc;
        }
    }
}

// ---------------- fp32 tiled GEMM, TMxTN microtile ----------------
// C[M,N] = A[M,K] @ B[K,N] (+bias, +relu). BK=16. Requires K%16==0, N%4==0.
template<int BM, int BN, int TM, int TN, bool ADD_BIAS, bool RELU>
__global__ __launch_bounds__((BM / TM) * (BN / TN)) void gemm_kernel(
        const float* __restrict__ A, const float* __restrict__ B,
        const float* __restrict__ bias, float* __restrict__ Cmat,
        int M, int N, int K) {
    constexpr int NT = (BM / TM) * (BN / TN);
    constexpr int BK = 16;
    constexpr int AV = BM * BK / 4 / NT;   // float4 loads per thread (A)
    constexpr int BV = BN * BK / 4 / NT;   // float4 loads per thread (B)
    __shared__ float As[BK][BM];
    __shared__ float Bs[BK][BN];

    const int t  = threadIdx.x;
    const int tm = t / (BN / TN);
    const int tn = t % (BN / TN);
    const int m0 = blockIdx.x * BM;
    const int n0 = blockIdx.y * BN;

    float acc[TM][TN] = {};

    for (int k0 = 0; k0 < K; k0 += BK) {
        #pragma unroll
        for (int v = 0; v < AV; ++v) {
            int idx = t + v * NT;          // index into BM x (BK/4) float4 grid
            int row = idx >> 2;
            int c4  = (idx & 3) * 4;
            float4 a4 = make_float4(0.f, 0.f, 0.f, 0.f);
            if (m0 + row < M)
                a4 = *(const float4*)&A[(size_t)(m0 + row) * K + k0 + c4];
            As[c4 + 0][row] = a4.x; As[c4 + 1][row] = a4.y;
            As[c4 + 2][row] = a4.z; As[c4 + 3][row] = a4.w;
        }
        #pragma unroll
        for (int v = 0; v < BV; ++v) {
            int idx = t + v * NT;          // index into BK x (BN/4) float4 grid
            int row = idx / (BN / 4);
            int col = (idx % (BN / 4)) * 4;
            float4 b4 = make_float4(0.f, 0.f, 0.f, 0.f);
            if (n0 + col < N)
                b4 = *(const float4*)&B[(size_t)(k0 + row) * N + n0 + col];
            *(float4*)&Bs[row][col] = b4;
        }
        __syncthreads();
        #pragma unroll
        for (int k = 0; k < BK; ++k) {
            float a[TM], b[TN];
            #pragma unroll
            for (int i = 0; i < TM; ++i) a[i] = As[k][tm * TM + i];
            #pragma unroll
            for (int j = 0; j < TN; ++j) b[j] = Bs[k][tn * TN + j];
            #pragma unroll
            for (int i = 0; i < TM; ++i)
                #pragma unroll
                for (int j = 0; j < TN; ++j)
                    acc[i][j] += a[i] * b[j];
        }
        __syncthreads();
    }

    #pragma unroll
    for (int i = 0; i < TM; ++i) {
        int row = m0 + tm * TM + i;
        if (row >= M) continue;
        #pragma unroll
        for (int j = 0; j < TN; j += 4) {
            int col = n0 + tn * TN + j;
            if (col >= N) continue;       // N%4==0, col%4==0 -> whole float4 in or out
            float4 v = make_float4(acc[i][j], acc[i][j + 1], acc[i][j + 2], acc[i][j + 3]);
            if (ADD_BIAS) {
                v.x += bias[col]; v.y += bias[col + 1];
                v.z += bias[col + 2]; v.w += bias[col + 3];
            }
            if (RELU) {
                v.x = fmaxf(v.x, 0.f); v.y = fmaxf(v.y, 0.f);
                v.z = fmaxf(v.z, 0.f); v.w = fmaxf(v.w, 0.f);
            }
            *(float4*)&Cmat[(size_t)row * N + col] = v;
        }
    }
}

extern "C" void kernel_launch(void* const* d_in, const int* in_sizes, int n_in,
                              void* d_out, int out_size, void* d_ws, size_t ws_size,
                              hipStream_t stream) {
    const float* x   = (const float*)d_in[0];
    const int*   ei  = (const int*)d_in[1];
    const float* W1  = (const float*)d_in[2];
    const float* b1  = (const float*)d_in[3];
    const float* W2  = (const float*)d_in[4];
    const float* b2  = (const float*)d_in[5];
    const float* Wfc = (const float*)d_in[6];
    const float* bfc = (const float*)d_in[7];
    float* out = (float*)d_out;

    const int n = N_NODES, E = N_EDGES;
    const int* src = ei;
    const int* dst = ei + E;

    char* ws = (char*)d_ws;
    int*   deg     = (int*)(ws + 0);             // 400 KB (reused as cursor)
    float* dinv    = (float*)(ws + 409600);      // 400 KB
    int*   rowptr  = (int*)(ws + 819200);        // ~400 KB
    int*   bsums   = (int*)(ws + 1228800);       // 512 B
    int*   csr_src = (int*)(ws + 1229312);       // 6.4 MB
    float* csr_w   = (float*)(ws + 7629312);     // 6.4 MB
    float* bufA    = (float*)(ws + 14029312);    // 51.2 MB  (aggx, then h1w2)
    float* bufB    = (float*)(ws + 65229312);    // 102.4 MB (h1, then h2)

    const int nb = (n + 1023) / 1024;  // 98 scan blocks

    // ---- CSR build (by dst) ----
    hipMemsetAsync(deg, 0, (size_t)n * sizeof(int), stream);
    deg_kernel<<<(E + 255) / 256, 256, 0, stream>>>(dst, deg, E);
    dinv_kernel<<<(n + 255) / 256, 256, 0, stream>>>(deg, dinv, n);
    scan_sums_kernel<<<nb, 256, 0, stream>>>(deg, bsums, n);
    scan_offsets_kernel<<<1, 128, 0, stream>>>(bsums, nb, rowptr + n);
    scan_final_kernel<<<nb, 256, 0, stream>>>(deg, bsums, rowptr, n);
    hipMemsetAsync(deg, 0, (size_t)n * sizeof(int), stream);  // deg -> cursor
    fill_kernel<<<(E + 255) / 256, 256, 0, stream>>>(src, dst, dinv, rowptr, deg, csr_src, csr_w, E);

    // ---- layer 1: aggx = A_hat @ x  [100k,128]  (gather FIRST — smaller footprint) ----
    gather_kernel<128, false, false><<<2048, 256, 0, stream>>>(
        rowptr, csr_src, csr_w, dinv, x, nullptr, bufA, n);
    // h1 = relu(aggx @ W1 + b1)  [100k,256]
    gemm_kernel<128, 128, 8, 8, true, true><<<dim3((n + 127) / 128, 2), 256, 0, stream>>>(
        bufA, W1, b1, bufB, n, 256, 128);

    // ---- layer 2: h1w2 = h1 @ W2  [100k,64]; gather + bias ----
    gemm_kernel<128, 64, 8, 8, false, false><<<dim3((n + 127) / 128, 1), 128, 0, stream>>>(
        bufB, W2, nullptr, bufA, n, 64, 256);
    gather_kernel<64, true, false><<<2048, 256, 0, stream>>>(
        rowptr, csr_src, csr_w, dinv, bufA, b2, bufB, n);

    // ---- FC: out = h2 @ Wfc + bfc  [100k,40] ----
    gemm_kernel<128, 64, 8, 8, true, false><<<dim3((n + 127) / 128, 1), 128, 0, stream>>>(
        bufB, Wfc, bfc, out, n, 40, 64);
}

// Round 5
// 590.936 us; speedup vs baseline: 10.8891x; 1.0967x over previous
//
#include <hip/hip_runtime.h>

#define N_NODES 100000
#define N_EDGES 1600000

// ---------------- degree ----------------
__global__ void deg_kernel(const int* __restrict__ dst, int* __restrict__ deg, int E) {
    int i = blockIdx.x * blockDim.x + threadIdx.x;
    if (i < E) atomicAdd(&deg[dst[i]], 1);
}

__global__ void dinv_kernel(const int* __restrict__ deg, float* __restrict__ dinv, int n) {
    int i = blockIdx.x * blockDim.x + threadIdx.x;
    if (i < n) dinv[i] = rsqrtf((float)(deg[i] + 1));   // +1 = self-loop
}

// ---------------- exclusive scan of deg -> rowptr (3 passes) ----------------
__global__ void scan_sums_kernel(const int* __restrict__ deg, int* __restrict__ bsums, int n) {
    __shared__ int sd[256];
    int t = threadIdx.x;
    int base = blockIdx.x * 1024 + t * 4;
    int s = 0;
    #pragma unroll
    for (int j = 0; j < 4; ++j) { int i = base + j; if (i < n) s += deg[i]; }
    sd[t] = s; __syncthreads();
    for (int off = 128; off > 0; off >>= 1) {
        if (t < off) sd[t] += sd[t + off];
        __syncthreads();
    }
    if (t == 0) bsums[blockIdx.x] = sd[0];
}

__global__ void scan_offsets_kernel(int* __restrict__ bsums, int nb, int* __restrict__ rowptr_tail) {
    __shared__ int sd[128];
    int t = threadIdx.x;
    int v = (t < nb) ? bsums[t] : 0;
    sd[t] = v; __syncthreads();
    for (int off = 1; off < 128; off <<= 1) {
        int x = (t >= off) ? sd[t - off] : 0;
        __syncthreads();
        sd[t] += x;
        __syncthreads();
    }
    if (t < nb) bsums[t] = sd[t] - v;      // exclusive
    if (t == 0) *rowptr_tail = N_EDGES;    // rowptr[n]
}

__global__ void scan_final_kernel(const int* __restrict__ deg, const int* __restrict__ bsums,
                                  int* __restrict__ rowptr, int n) {
    __shared__ int sd[256];
    int t = threadIdx.x;
    int base = blockIdx.x * 1024 + t * 4;
    int v[4], pre[4], s = 0;
    #pragma unroll
    for (int j = 0; j < 4; ++j) {
        int i = base + j;
        v[j] = (i < n) ? deg[i] : 0;
        pre[j] = s; s += v[j];
    }
    sd[t] = s;
    int mine = s;
    __syncthreads();
    for (int off = 1; off < 256; off <<= 1) {
        int x = (t >= off) ? sd[t - off] : 0;
        __syncthreads();
        sd[t] += x;
        __syncthreads();
    }
    int excl = sd[t] - mine + bsums[blockIdx.x];
    #pragma unroll
    for (int j = 0; j < 4; ++j) {
        int i = base + j;
        if (i < n) rowptr[i] = excl + pre[j];
    }
}

// ---------------- counting-sort fill: (src, weight) packed as int2 ----------------
__global__ void fill_kernel(const int* __restrict__ src, const int* __restrict__ dst,
                            const float* __restrict__ dinv, const int* __restrict__ rowptr,
                            int* __restrict__ cursor, int2* __restrict__ csr, int E) {
    int i = blockIdx.x * blockDim.x + threadIdx.x;
    if (i >= E) return;
    int s = src[i], d = dst[i];
    int pos = atomicAdd(&cursor[d], 1);
    float w = dinv[s] * dinv[d];
    csr[rowptr[d] + pos] = make_int2(s, __float_as_int(w));
}

// ---------------- gather (one wave per dst node), 4x-unrolled edge loop ----------------
// F=128: lane owns float2. F=64: lane owns 1 float. Self-loop folded into init.
template<int F, bool BIAS, bool RELU>
__global__ void gather_kernel(const int* __restrict__ rowptr, const int2* __restrict__ csr,
                              const float* __restrict__ dinv,
                              const float* __restrict__ xw, const float* __restrict__ bias,
                              float* __restrict__ out, int n) {
    const int lane = threadIdx.x & 63;
    const int wid0 = (blockIdx.x * blockDim.x + threadIdx.x) >> 6;
    const int nwav = (gridDim.x * blockDim.x) >> 6;
    for (int node = wid0; node < n; node += nwav) {
        float di = dinv[node];
        float selfw = di * di;
        int e0 = rowptr[node], e1 = rowptr[node + 1];
        if (F == 128) {
            const float2 sv = *(const float2*)&xw[(size_t)node * F + lane * 2];
            float ax = sv.x * selfw, ay = sv.y * selfw;
            int e = e0;
            for (; e + 4 <= e1; e += 4) {
                int2 p0 = csr[e + 0], p1 = csr[e + 1], p2 = csr[e + 2], p3 = csr[e + 3];
                float2 v0 = *(const float2*)&xw[(size_t)p0.x * F + lane * 2];
                float2 v1 = *(const float2*)&xw[(size_t)p1.x * F + lane * 2];
                float2 v2 = *(const float2*)&xw[(size_t)p2.x * F + lane * 2];
                float2 v3 = *(const float2*)&xw[(size_t)p3.x * F + lane * 2];
                float w0 = __int_as_float(p0.y), w1 = __int_as_float(p1.y);
                float w2 = __int_as_float(p2.y), w3 = __int_as_float(p3.y);
                ax += v0.x * w0; ay += v0.y * w0;
                ax += v1.x * w1; ay += v1.y * w1;
                ax += v2.x * w2; ay += v2.y * w2;
                ax += v3.x * w3; ay += v3.y * w3;
            }
            for (; e < e1; ++e) {
                int2 p = csr[e];
                float w = __int_as_float(p.y);
                const float2 v = *(const float2*)&xw[(size_t)p.x * F + lane * 2];
                ax += v.x * w; ay += v.y * w;
            }
            if (BIAS) { const float2 bb = *(const float2*)&bias[lane * 2]; ax += bb.x; ay += bb.y; }
            if (RELU) { ax = fmaxf(ax, 0.f); ay = fmaxf(ay, 0.f); }
            *(float2*)&out[(size_t)node * F + lane * 2] = make_float2(ax, ay);
        } else {  // F == 64
            float acc = xw[(size_t)node * F + lane] * selfw;
            int e = e0;
            for (; e + 4 <= e1; e += 4) {
                int2 p0 = csr[e + 0], p1 = csr[e + 1], p2 = csr[e + 2], p3 = csr[e + 3];
                float v0 = xw[(size_t)p0.x * F + lane];
                float v1 = xw[(size_t)p1.x * F + lane];
                float v2 = xw[(size_t)p2.x * F + lane];
                float v3 = xw[(size_t)p3.x * F + lane];
                acc += v0 * __int_as_float(p0.y);
                acc += v1 * __int_as_float(p1.y);
                acc += v2 * __int_as_float(p2.y);
                acc += v3 * __int_as_float(p3.y);
            }
            for (; e < e1; ++e) {
                int2 p = csr[e];
                acc += xw[(size_t)p.x * F + lane] * __int_as_float(p.y);
            }
            if (BIAS) acc += bias[lane];
            if (RELU) acc = fmaxf(acc, 0.f);
            out[(size_t)node * F + lane] = acc;
        }
    }
}

// ---------------- fp32 tiled GEMM, TMxTN microtile ----------------
// C[M,N] = A[M,K] @ B[K,N] (+bias, +relu). Requires K%BK==0, N%4==0.
template<int BM, int BN, int BK, int TM, int TN, bool ADD_BIAS, bool RELU>
__global__ __launch_bounds__((BM / TM) * (BN / TN)) void gemm_kernel(
        const float* __restrict__ A, const float* __restrict__ B,
        const float* __restrict__ bias, float* __restrict__ Cmat,
        int M, int N, int K) {
    constexpr int NT = (BM / TM) * (BN / TN);
    constexpr int AV = BM * BK / 4 / NT;   // float4 loads per thread (A)
    constexpr int BV = BN * BK / 4 / NT;   // float4 loads per thread (B)
    constexpr int KV = BK / 4;             // float4 per A row
    __shared__ float As[BK][BM];
    __shared__ float Bs[BK][BN];

    const int t  = threadIdx.x;
    const int tm = t / (BN / TN);
    const int tn = t % (BN / TN);
    const int m0 = blockIdx.x * BM;
    const int n0 = blockIdx.y * BN;

    float acc[TM][TN] = {};

    for (int k0 = 0; k0 < K; k0 += BK) {
        #pragma unroll
        for (int v = 0; v < AV; ++v) {
            int idx = t + v * NT;          // index into BM x KV float4 grid
            int row = idx / KV;
            int c4  = (idx % KV) * 4;
            float4 a4 = make_float4(0.f, 0.f, 0.f, 0.f);
            if (m0 + row < M)
                a4 = *(const float4*)&A[(size_t)(m0 + row) * K + k0 + c4];
            As[c4 + 0][row] = a4.x; As[c4 + 1][row] = a4.y;
            As[c4 + 2][row] = a4.z; As[c4 + 3][row] = a4.w;
        }
        #pragma unroll
        for (int v = 0; v < BV; ++v) {
            int idx = t + v * NT;          // index into BK x (BN/4) float4 grid
            int row = idx / (BN / 4);
            int col = (idx % (BN / 4)) * 4;
            float4 b4 = make_float4(0.f, 0.f, 0.f, 0.f);
            if (n0 + col < N)
                b4 = *(const float4*)&B[(size_t)(k0 + row) * N + n0 + col];
            *(float4*)&Bs[row][col] = b4;
        }
        __syncthreads();
        #pragma unroll
        for (int k = 0; k < BK; ++k) {
            float a[TM], b[TN];
            #pragma unroll
            for (int i = 0; i < TM; ++i) a[i] = As[k][tm * TM + i];
            #pragma unroll
            for (int j = 0; j < TN; ++j) b[j] = Bs[k][tn * TN + j];
            #pragma unroll
            for (int i = 0; i < TM; ++i)
                #pragma unroll
                for (int j = 0; j < TN; ++j)
                    acc[i][j] += a[i] * b[j];
        }
        __syncthreads();
    }

    #pragma unroll
    for (int i = 0; i < TM; ++i) {
        int row = m0 + tm * TM + i;
        if (row >= M) continue;
        #pragma unroll
        for (int j = 0; j < TN; j += 4) {
            int col = n0 + tn * TN + j;
            if (col >= N) continue;       // N%4==0, col%4==0 -> whole float4 in or out
            float4 v = make_float4(acc[i][j], acc[i][j + 1], acc[i][j + 2], acc[i][j + 3]);
            if (ADD_BIAS) {
                v.x += bias[col]; v.y += bias[col + 1];
                v.z += bias[col + 2]; v.w += bias[col + 3];
            }
            if (RELU) {
                v.x = fmaxf(v.x, 0.f); v.y = fmaxf(v.y, 0.f);
                v.z = fmaxf(v.z, 0.f); v.w = fmaxf(v.w, 0.f);
            }
            *(float4*)&Cmat[(size_t)row * N + col] = v;
        }
    }
}

extern "C" void kernel_launch(void* const* d_in, const int* in_sizes, int n_in,
                              void* d_out, int out_size, void* d_ws, size_t ws_size,
                              hipStream_t stream) {
    const float* x   = (const float*)d_in[0];
    const int*   ei  = (const int*)d_in[1];
    const float* W1  = (const float*)d_in[2];
    const float* b1  = (const float*)d_in[3];
    const float* W2  = (const float*)d_in[4];
    const float* b2  = (const float*)d_in[5];
    const float* Wfc = (const float*)d_in[6];
    const float* bfc = (const float*)d_in[7];
    float* out = (float*)d_out;

    const int n = N_NODES, E = N_EDGES;
    const int* src = ei;
    const int* dst = ei + E;

    char* ws = (char*)d_ws;
    int*   deg     = (int*)(ws + 0);             // 400 KB (reused as cursor)
    float* dinv    = (float*)(ws + 409600);      // 400 KB
    int*   rowptr  = (int*)(ws + 819200);        // ~400 KB
    int*   bsums   = (int*)(ws + 1228800);       // 512 B
    int2*  csr     = (int2*)(ws + 1229312);      // 12.8 MB (packed src+w)
    float* bufA    = (float*)(ws + 14029312);    // 51.2 MB  (aggx, then h1w2)
    float* bufB    = (float*)(ws + 65229312);    // 102.4 MB (h1, then h2)

    const int nb = (n + 1023) / 1024;  // 98 scan blocks

    // ---- CSR build (by dst) ----
    hipMemsetAsync(deg, 0, (size_t)n * sizeof(int), stream);
    deg_kernel<<<(E + 255) / 256, 256, 0, stream>>>(dst, deg, E);
    dinv_kernel<<<(n + 255) / 256, 256, 0, stream>>>(deg, dinv, n);
    scan_sums_kernel<<<nb, 256, 0, stream>>>(deg, bsums, n);
    scan_offsets_kernel<<<1, 128, 0, stream>>>(bsums, nb, rowptr + n);
    scan_final_kernel<<<nb, 256, 0, stream>>>(deg, bsums, rowptr, n);
    hipMemsetAsync(deg, 0, (size_t)n * sizeof(int), stream);  // deg -> cursor
    fill_kernel<<<(E + 255) / 256, 256, 0, stream>>>(src, dst, dinv, rowptr, deg, csr, E);

    // ---- layer 1: aggx = A_hat @ x  [100k,128]  (gather FIRST — smaller footprint) ----
    gather_kernel<128, false, false><<<2048, 256, 0, stream>>>(
        rowptr, csr, dinv, x, nullptr, bufA, n);
    // h1 = relu(aggx @ W1 + b1)  [100k,256]
    gemm_kernel<128, 128, 32, 8, 8, true, true><<<dim3((n + 127) / 128, 2), 256, 0, stream>>>(
        bufA, W1, b1, bufB, n, 256, 128);

    // ---- layer 2: h1w2 = h1 @ W2  [100k,64]; gather + bias ----
    gemm_kernel<128, 64, 32, 8, 8, false, false><<<dim3((n + 127) / 128, 1), 128, 0, stream>>>(
        bufB, W2, nullptr, bufA, n, 64, 256);
    gather_kernel<64, true, false><<<2048, 256, 0, stream>>>(
        rowptr, csr, dinv, bufA, b2, bufB, n);

    // ---- FC: out = h2 @ Wfc + bfc  [100k,40] ----
    gemm_kernel<128, 64, 32, 8, 8, true, false><<<dim3((n + 127) / 128, 1), 128, 0, stream>>>(
        bufB, Wfc, bfc, out, n, 40, 64);
}